// Round 1
// baseline (2174.786 us; speedup 1.0000x reference)
//
#include <hip/hip_runtime.h>
#include <hip/hip_bf16.h>
#include <math.h>

#define RES   160
#define RES2  (160*160)
#define RES3  (160*160*160)

typedef __attribute__((ext_vector_type(8))) short s16x8;
typedef __attribute__((ext_vector_type(4))) float f32x4;
typedef __attribute__((ext_vector_type(4))) int   i32x4;

__device__ __forceinline__ unsigned short f2bf(float x) {
    union { float f; unsigned u; } v; v.f = x;
    unsigned r = v.u + 0x7FFFu + ((v.u >> 16) & 1u);
    return (unsigned short)(r >> 16);
}
__device__ __forceinline__ unsigned pack2(float lo, float hi) {
    return (unsigned)f2bf(lo) | ((unsigned)f2bf(hi) << 16);
}

// LDS layout (shorts): padded-K transposed weights for conflict-light ds_read_b128
// w0T[n][k]: 128 x 72  (k<36 real, rest 0)
// w1T[n][k]: 128 x 136 (k<128 real)
// w2T[n][k]: 16  x 136 (n<3 real)
__global__ __launch_bounds__(256, 2) void dvgo_fused(
    const float* __restrict__ pts, const float* __restrict__ vdirs,
    const float* __restrict__ dgrid, const float* __restrict__ cgrid,
    const float* __restrict__ w0, const float* __restrict__ b0,
    const float* __restrict__ w1, const float* __restrict__ b1,
    const float* __restrict__ w2, const float* __restrict__ b2,
    float* __restrict__ out)
{
    __shared__ short w0T[128*72];
    __shared__ short w1T[128*136];
    __shared__ short w2T[16*136];
    __shared__ float b0s[128];
    __shared__ float b1s[128];
    __shared__ float b2s[16];
    __shared__ float diff[256*3];
    __shared__ short hbuf[4][16*136];

    const int tid = threadIdx.x;

    // ---------- phase A: stage weights (bf16, transposed, padded) ----------
    for (int i = tid; i < 128*72; i += 256) {
        int n = i / 72, k = i % 72;
        w0T[i] = (k < 36) ? (short)f2bf(w0[k*128 + n]) : (short)0;
    }
    for (int i = tid; i < 128*136; i += 256) {
        int n = i / 136, k = i % 136;
        w1T[i] = (k < 128) ? (short)f2bf(w1[k*128 + n]) : (short)0;
    }
    for (int i = tid; i < 16*136; i += 256) {
        int n = i / 136, k = i % 136;
        w2T[i] = (n < 3 && k < 128) ? (short)f2bf(w2[k*3 + n]) : (short)0;
    }
    if (tid < 128) { b0s[tid] = b0[tid]; b1s[tid] = b1[tid]; }
    if (tid < 16)  { b2s[tid] = (tid < 3) ? b2[tid] : 0.0f; }

    // ---------- phase B: per-thread gather + feature build ----------
    const int p = blockIdx.x * 256 + tid;
    float P0 = pts[p*3+0], P1 = pts[p*3+1], P2 = pts[p*3+2];
    float V0 = vdirs[p*3+0], V1 = vdirs[p*3+1], V2 = vdirs[p*3+2];

    int   ii[3];
    float ff[3];
    float Pv[3] = {P0, P1, P2};
    #pragma unroll
    for (int d = 0; d < 3; ++d) {
        float u = (Pv[d] + 1.0f) * 79.5f;          // (p - min)/(max-min) * (res-1)
        u = fminf(fmaxf(u, 0.0f), 159.0f);
        int i0 = (int)u;                           // floor (u >= 0)
        if (i0 > 158) i0 = 158;
        ii[d] = i0;
        ff[d] = u - (float)i0;
    }
    const float fx = ff[0], fy = ff[1], fz = ff[2];
    const float wxy0 = (1.0f-fx)*(1.0f-fy);
    const float wxy1 = (1.0f-fx)*fy;
    const float wxy2 = fx*(1.0f-fy);
    const float wxy3 = fx*fy;
    const int base = (ii[0]*RES + ii[1])*RES + ii[2];
    const int o0 = base, o1 = base + RES, o2 = base + RES2, o3 = base + RES2 + RES;

    auto tl = [&](const float* __restrict__ g) -> float {
        float a0 = g[o0], a1 = g[o0+1];
        float c0 = g[o1], c1 = g[o1+1];
        float d0 = g[o2], d1 = g[o2+1];
        float e0 = g[o3], e1 = g[o3+1];
        float v0 = a0 + fz*(a1-a0);
        float v1 = c0 + fz*(c1-c0);
        float v2 = d0 + fz*(d1-d0);
        float v3 = e0 + fz*(e1-e0);
        return wxy0*v0 + wxy1*v1 + wxy2*v2 + wxy3*v3;
    };

    float dens = tl(dgrid);
    float col[12];
    #pragma unroll
    for (int c = 0; c < 12; ++c) col[c] = tl(cgrid + (long)c * RES3);

    out[p*4 + 3] = dens;                      // density channel, f32 exact
    diff[tid*3+0] = col[0];
    diff[tid*3+1] = col[1];
    diff[tid*3+2] = col[2];

    // feature vector: [k0_view(9), v(3), sin(2^k v)(12), cos(2^k v)(12)] -> pad to 64
    float ft[36];
    #pragma unroll
    for (int j = 0; j < 9; ++j) ft[j] = col[3+j];
    ft[9] = V0; ft[10] = V1; ft[11] = V2;
    float Vv[3] = {V0, V1, V2};
    #pragma unroll
    for (int k = 0; k < 4; ++k) {
        float s = (float)(1 << k);
        #pragma unroll
        for (int d = 0; d < 3; ++d) {
            float a = Vv[d] * s;
            ft[12 + 3*k + d] = __sinf(a);
            ft[24 + 3*k + d] = __cosf(a);
        }
    }
    unsigned fpk[32];
    #pragma unroll
    for (int j = 0; j < 18; ++j) fpk[j] = pack2(ft[2*j], ft[2*j+1]);
    #pragma unroll
    for (int j = 18; j < 32; ++j) fpk[j] = 0u;

    __syncthreads();   // weights staged; everything after is wave-private

    // ---------- phase C: per-wave MFMA MLP over 4 M=16 tiles ----------
    const int lane = tid & 63;
    const int wv   = tid >> 6;
    const int row  = lane & 15;     // A-row / B-col / D-col index
    const int seg  = lane >> 4;     // 0..3
    short* hb = &hbuf[wv][0];

    #pragma unroll 1
    for (int t = 0; t < 4; ++t) {
        // stage this tile's 16 feature rows (owned by lanes seg==t of this wave)
        if (seg == t) {
            #pragma unroll
            for (int j = 0; j < 8; ++j) {
                i32x4 v = { (int)fpk[4*j+0], (int)fpk[4*j+1],
                            (int)fpk[4*j+2], (int)fpk[4*j+3] };
                *(i32x4*)&hb[row*136 + j*8] = v;
            }
        }

        // ---- layer 0: [16x64] @ [64x128] ----
        s16x8 a00 = *(const s16x8*)&hb[row*136 +  0 + seg*8];
        s16x8 a01 = *(const s16x8*)&hb[row*136 + 32 + seg*8];
        f32x4 acc0[8];
        #pragma unroll
        for (int nt = 0; nt < 8; ++nt) {
            float bias = b0s[nt*16 + row];
            f32x4 acc = { bias, bias, bias, bias };
            s16x8 bb0 = *(const s16x8*)&w0T[(nt*16+row)*72 +  0 + seg*8];
            s16x8 bb1 = *(const s16x8*)&w0T[(nt*16+row)*72 + 32 + seg*8];
            acc = __builtin_amdgcn_mfma_f32_16x16x32_bf16(a00, bb0, acc, 0, 0, 0);
            acc = __builtin_amdgcn_mfma_f32_16x16x32_bf16(a01, bb1, acc, 0, 0, 0);
            acc0[nt] = acc;
        }
        #pragma unroll
        for (int nt = 0; nt < 8; ++nt) {
            #pragma unroll
            for (int r = 0; r < 4; ++r) {
                float v = acc0[nt][r];
                v = v > 0.0f ? v : 0.0f;
                hb[(seg*4+r)*136 + nt*16 + row] = (short)f2bf(v);
            }
        }

        // ---- layer 1: [16x128] @ [128x128] ----
        s16x8 a1[4];
        #pragma unroll
        for (int ks = 0; ks < 4; ++ks)
            a1[ks] = *(const s16x8*)&hb[row*136 + ks*32 + seg*8];
        f32x4 acc1[8];
        #pragma unroll
        for (int nt = 0; nt < 8; ++nt) {
            float bias = b1s[nt*16 + row];
            f32x4 acc = { bias, bias, bias, bias };
            #pragma unroll
            for (int ks = 0; ks < 4; ++ks) {
                s16x8 bb = *(const s16x8*)&w1T[(nt*16+row)*136 + ks*32 + seg*8];
                acc = __builtin_amdgcn_mfma_f32_16x16x32_bf16(a1[ks], bb, acc, 0, 0, 0);
            }
            acc1[nt] = acc;
        }
        #pragma unroll
        for (int nt = 0; nt < 8; ++nt) {
            #pragma unroll
            for (int r = 0; r < 4; ++r) {
                float v = acc1[nt][r];
                v = v > 0.0f ? v : 0.0f;
                hb[(seg*4+r)*136 + nt*16 + row] = (short)f2bf(v);
            }
        }

        // ---- layer 2: [16x128] @ [128x16(pad of 3)] ----
        s16x8 a2[4];
        #pragma unroll
        for (int ks = 0; ks < 4; ++ks)
            a2[ks] = *(const s16x8*)&hb[row*136 + ks*32 + seg*8];
        float bias2 = b2s[row];
        f32x4 acc2 = { bias2, bias2, bias2, bias2 };
        #pragma unroll
        for (int ks = 0; ks < 4; ++ks) {
            s16x8 bb = *(const s16x8*)&w2T[row*136 + ks*32 + seg*8];
            acc2 = __builtin_amdgcn_mfma_f32_16x16x32_bf16(a2[ks], bb, acc2, 0, 0, 0);
        }

        // ---- epilogue: sigmoid(logit + diffuse) ----
        if (row < 3) {
            #pragma unroll
            for (int r = 0; r < 4; ++r) {
                int pidx = t*16 + seg*4 + r;          // index within this wave's 64 pts
                int pl   = wv*64 + pidx;              // block-local point
                float x  = acc2[r] + diff[pl*3 + row];
                float sg = 1.0f / (1.0f + __expf(-x));
                out[(blockIdx.x*256 + pl)*4 + row] = sg;
            }
        }
    }
}

extern "C" void kernel_launch(void* const* d_in, const int* in_sizes, int n_in,
                              void* d_out, int out_size, void* d_ws, size_t ws_size,
                              hipStream_t stream) {
    const float* pts = (const float*)d_in[0];
    const float* vd  = (const float*)d_in[1];
    const float* dg  = (const float*)d_in[2];
    const float* cg  = (const float*)d_in[3];
    const float* w0  = (const float*)d_in[4];
    const float* b0  = (const float*)d_in[5];
    const float* w1  = (const float*)d_in[6];
    const float* b1  = (const float*)d_in[7];
    const float* w2  = (const float*)d_in[8];
    const float* b2  = (const float*)d_in[9];
    float* out = (float*)d_out;

    const int n = in_sizes[0] / 3;        // 2097152 points
    const int blocks = n / 256;           // 8192, exact
    dvgo_fused<<<blocks, 256, 0, stream>>>(pts, vd, dg, cg, w0, b0, w1, b1, w2, b2, out);
}

// Round 2
// 706.220 us; speedup vs baseline: 3.0795x; 3.0795x over previous
//
#include <hip/hip_runtime.h>
#include <hip/hip_bf16.h>
#include <math.h>

#define RES   160
#define RES2  (160*160)
#define RES3  (160*160*160)
#define TG_ELEMS ((size_t)RES3 * 16)           // shorts
#define TG_BYTES (TG_ELEMS * 2)                // 131,072,000 B

typedef __attribute__((ext_vector_type(8))) short s16x8;
typedef __attribute__((ext_vector_type(4))) float f32x4;
typedef __attribute__((ext_vector_type(4))) int   i32x4;

__device__ __forceinline__ unsigned short f2bf(float x) {
    union { float f; unsigned u; } v; v.f = x;
    unsigned r = v.u + 0x7FFFu + ((v.u >> 16) & 1u);
    return (unsigned short)(r >> 16);
}
__device__ __forceinline__ unsigned pack2(float lo, float hi) {
    return (unsigned)f2bf(lo) | ((unsigned)f2bf(hi) << 16);
}
__device__ __forceinline__ float bf_lo(unsigned u) {
    union { unsigned u; float f; } v; v.u = u << 16; return v.f;
}
__device__ __forceinline__ float bf_hi(unsigned u) {
    union { unsigned u; float f; } v; v.u = u & 0xFFFF0000u; return v.f;
}

// ---------------- transpose: [C,X,Y,Z] f32 -> [X,Y,Z,16] bf16 ----------------
__global__ __launch_bounds__(256) void make_tg(
    const float* __restrict__ dgrid, const float* __restrict__ cgrid,
    short* __restrict__ tg)
{
    const int v = blockIdx.x * 256 + threadIdx.x;   // voxel id, grid sized exactly
    float vals[13];
    #pragma unroll
    for (int c = 0; c < 12; ++c) vals[c] = cgrid[(size_t)c * RES3 + v];
    vals[12] = dgrid[v];

    i32x4 r0 = { (int)pack2(vals[0], vals[1]),  (int)pack2(vals[2],  vals[3]),
                 (int)pack2(vals[4], vals[5]),  (int)pack2(vals[6],  vals[7]) };
    i32x4 r1 = { (int)pack2(vals[8], vals[9]),  (int)pack2(vals[10], vals[11]),
                 (int)pack2(vals[12], 0.0f),    0 };
    *(i32x4*)&tg[(size_t)v * 16 + 0] = r0;
    *(i32x4*)&tg[(size_t)v * 16 + 8] = r1;
}

// ---------------- fused gather + MLP ----------------
// LDS: padded-K transposed weights for conflict-light ds_read_b128
template<bool TG>
__global__ __launch_bounds__(256, 2) void dvgo_fused(
    const float* __restrict__ pts, const float* __restrict__ vdirs,
    const float* __restrict__ dgrid, const float* __restrict__ cgrid,
    const short* __restrict__ tg,
    const float* __restrict__ w0, const float* __restrict__ b0,
    const float* __restrict__ w1, const float* __restrict__ b1,
    const float* __restrict__ w2, const float* __restrict__ b2,
    float* __restrict__ out)
{
    __shared__ short w0T[128*72];
    __shared__ short w1T[128*136];
    __shared__ short w2T[16*136];
    __shared__ float b0s[128];
    __shared__ float b1s[128];
    __shared__ float b2s[16];
    __shared__ float diff[256*3];
    __shared__ short hbuf[4][16*136];

    const int tid = threadIdx.x;

    // ---------- phase A: stage weights (bf16, transposed, padded) ----------
    for (int i = tid; i < 128*72; i += 256) {
        int n = i / 72, k = i % 72;
        w0T[i] = (k < 36) ? (short)f2bf(w0[k*128 + n]) : (short)0;
    }
    for (int i = tid; i < 128*136; i += 256) {
        int n = i / 136, k = i % 136;
        w1T[i] = (k < 128) ? (short)f2bf(w1[k*128 + n]) : (short)0;
    }
    for (int i = tid; i < 16*136; i += 256) {
        int n = i / 136, k = i % 136;
        w2T[i] = (n < 3 && k < 128) ? (short)f2bf(w2[k*3 + n]) : (short)0;
    }
    if (tid < 128) { b0s[tid] = b0[tid]; b1s[tid] = b1[tid]; }
    if (tid < 16)  { b2s[tid] = (tid < 3) ? b2[tid] : 0.0f; }

    // ---------- phase B: per-thread gather + feature build ----------
    const int p = blockIdx.x * 256 + tid;
    float P0 = pts[p*3+0], P1 = pts[p*3+1], P2 = pts[p*3+2];
    float V0 = vdirs[p*3+0], V1 = vdirs[p*3+1], V2 = vdirs[p*3+2];

    int   ii[3];
    float ff[3];
    float Pv[3] = {P0, P1, P2};
    #pragma unroll
    for (int d = 0; d < 3; ++d) {
        float u = (Pv[d] + 1.0f) * 79.5f;
        u = fminf(fmaxf(u, 0.0f), 159.0f);
        int i0 = (int)u;
        if (i0 > 158) i0 = 158;
        ii[d] = i0;
        ff[d] = u - (float)i0;
    }
    const float fx = ff[0], fy = ff[1], fz = ff[2];
    const float wxy0 = (1.0f-fx)*(1.0f-fy);
    const float wxy1 = (1.0f-fx)*fy;
    const float wxy2 = fx*(1.0f-fy);
    const float wxy3 = fx*fy;

    float dens;
    float col[12];

    if (TG) {
        const int base16 = ((ii[0]*RES + ii[1])*RES + ii[2]) * 16;
        const short* q00 = tg + base16;
        const short* q01 = q00 + RES*16;
        const short* q10 = q00 + RES2*16;
        const short* q11 = q10 + RES*16;

        float cv[13];
        #pragma unroll
        for (int c = 0; c < 13; ++c) cv[c] = 0.0f;

        const short* qs[4] = { q00, q01, q10, q11 };
        const float  ws[4] = { wxy0, wxy1, wxy2, wxy3 };
        #pragma unroll
        for (int cn = 0; cn < 4; ++cn) {
            const short* q = qs[cn];
            const float  w = ws[cn];
            i32x4 u0 = *(const i32x4*)(q);       // z voxel, ch0..7
            i32x4 u1 = *(const i32x4*)(q + 8);   // z voxel, ch8..15
            i32x4 u2 = *(const i32x4*)(q + 16);  // z+1 voxel, ch0..7
            i32x4 u3 = *(const i32x4*)(q + 24);  // z+1 voxel, ch8..15
            unsigned a[8] = { (unsigned)u0[0], (unsigned)u0[1], (unsigned)u0[2], (unsigned)u0[3],
                              (unsigned)u1[0], (unsigned)u1[1], (unsigned)u1[2], (unsigned)u1[3] };
            unsigned b[8] = { (unsigned)u2[0], (unsigned)u2[1], (unsigned)u2[2], (unsigned)u2[3],
                              (unsigned)u3[0], (unsigned)u3[1], (unsigned)u3[2], (unsigned)u3[3] };
            #pragma unroll
            for (int c = 0; c < 13; ++c) {
                float va = (c & 1) ? bf_hi(a[c >> 1]) : bf_lo(a[c >> 1]);
                float vb = (c & 1) ? bf_hi(b[c >> 1]) : bf_lo(b[c >> 1]);
                cv[c] += w * (va + fz * (vb - va));
            }
        }
        #pragma unroll
        for (int c = 0; c < 12; ++c) col[c] = cv[c];
        dens = cv[12];
    } else {
        const int base = (ii[0]*RES + ii[1])*RES + ii[2];
        const int o0 = base, o1 = base + RES, o2 = base + RES2, o3 = base + RES2 + RES;
        auto tl = [&](const float* __restrict__ g) -> float {
            float a0 = g[o0], a1 = g[o0+1];
            float c0 = g[o1], c1 = g[o1+1];
            float d0 = g[o2], d1 = g[o2+1];
            float e0 = g[o3], e1 = g[o3+1];
            float v0 = a0 + fz*(a1-a0);
            float v1 = c0 + fz*(c1-c0);
            float v2 = d0 + fz*(d1-d0);
            float v3 = e0 + fz*(e1-e0);
            return wxy0*v0 + wxy1*v1 + wxy2*v2 + wxy3*v3;
        };
        dens = tl(dgrid);
        #pragma unroll
        for (int c = 0; c < 12; ++c) col[c] = tl(cgrid + (size_t)c * RES3);
    }

    out[p*4 + 3] = dens;
    diff[tid*3+0] = col[0];
    diff[tid*3+1] = col[1];
    diff[tid*3+2] = col[2];

    // feature vector: [k0_view(9), v(3), sin(2^k v)(12), cos(2^k v)(12)] -> pad to 64
    float ft[36];
    #pragma unroll
    for (int j = 0; j < 9; ++j) ft[j] = col[3+j];
    ft[9] = V0; ft[10] = V1; ft[11] = V2;
    float Vv[3] = {V0, V1, V2};
    #pragma unroll
    for (int k = 0; k < 4; ++k) {
        float s = (float)(1 << k);
        #pragma unroll
        for (int d = 0; d < 3; ++d) {
            float a = Vv[d] * s;
            ft[12 + 3*k + d] = __sinf(a);
            ft[24 + 3*k + d] = __cosf(a);
        }
    }
    unsigned fpk[32];
    #pragma unroll
    for (int j = 0; j < 18; ++j) fpk[j] = pack2(ft[2*j], ft[2*j+1]);
    #pragma unroll
    for (int j = 18; j < 32; ++j) fpk[j] = 0u;

    __syncthreads();   // weights staged; everything after is wave-private

    // ---------- phase C: per-wave MFMA MLP over 4 M=16 tiles ----------
    const int lane = tid & 63;
    const int wv   = tid >> 6;
    const int row  = lane & 15;
    const int seg  = lane >> 4;
    short* hb = &hbuf[wv][0];

    #pragma unroll 1
    for (int t = 0; t < 4; ++t) {
        if (seg == t) {
            #pragma unroll
            for (int j = 0; j < 8; ++j) {
                i32x4 v = { (int)fpk[4*j+0], (int)fpk[4*j+1],
                            (int)fpk[4*j+2], (int)fpk[4*j+3] };
                *(i32x4*)&hb[row*136 + j*8] = v;
            }
        }

        // ---- layer 0: [16x64] @ [64x128] ----
        s16x8 a00 = *(const s16x8*)&hb[row*136 +  0 + seg*8];
        s16x8 a01 = *(const s16x8*)&hb[row*136 + 32 + seg*8];
        f32x4 acc0[8];
        #pragma unroll
        for (int nt = 0; nt < 8; ++nt) {
            float bias = b0s[nt*16 + row];
            f32x4 acc = { bias, bias, bias, bias };
            s16x8 bb0 = *(const s16x8*)&w0T[(nt*16+row)*72 +  0 + seg*8];
            s16x8 bb1 = *(const s16x8*)&w0T[(nt*16+row)*72 + 32 + seg*8];
            acc = __builtin_amdgcn_mfma_f32_16x16x32_bf16(a00, bb0, acc, 0, 0, 0);
            acc = __builtin_amdgcn_mfma_f32_16x16x32_bf16(a01, bb1, acc, 0, 0, 0);
            acc0[nt] = acc;
        }
        #pragma unroll
        for (int nt = 0; nt < 8; ++nt) {
            #pragma unroll
            for (int r = 0; r < 4; ++r) {
                float v = acc0[nt][r];
                v = v > 0.0f ? v : 0.0f;
                hb[(seg*4+r)*136 + nt*16 + row] = (short)f2bf(v);
            }
        }

        // ---- layer 1: [16x128] @ [128x128] ----
        s16x8 a1[4];
        #pragma unroll
        for (int ks = 0; ks < 4; ++ks)
            a1[ks] = *(const s16x8*)&hb[row*136 + ks*32 + seg*8];
        f32x4 acc1[8];
        #pragma unroll
        for (int nt = 0; nt < 8; ++nt) {
            float bias = b1s[nt*16 + row];
            f32x4 acc = { bias, bias, bias, bias };
            #pragma unroll
            for (int ks = 0; ks < 4; ++ks) {
                s16x8 bb = *(const s16x8*)&w1T[(nt*16+row)*136 + ks*32 + seg*8];
                acc = __builtin_amdgcn_mfma_f32_16x16x32_bf16(a1[ks], bb, acc, 0, 0, 0);
            }
            acc1[nt] = acc;
        }
        #pragma unroll
        for (int nt = 0; nt < 8; ++nt) {
            #pragma unroll
            for (int r = 0; r < 4; ++r) {
                float v = acc1[nt][r];
                v = v > 0.0f ? v : 0.0f;
                hb[(seg*4+r)*136 + nt*16 + row] = (short)f2bf(v);
            }
        }

        // ---- layer 2: [16x128] @ [128x16(pad of 3)] ----
        s16x8 a2[4];
        #pragma unroll
        for (int ks = 0; ks < 4; ++ks)
            a2[ks] = *(const s16x8*)&hb[row*136 + ks*32 + seg*8];
        float bias2 = b2s[row];
        f32x4 acc2 = { bias2, bias2, bias2, bias2 };
        #pragma unroll
        for (int ks = 0; ks < 4; ++ks) {
            s16x8 bb = *(const s16x8*)&w2T[row*136 + ks*32 + seg*8];
            acc2 = __builtin_amdgcn_mfma_f32_16x16x32_bf16(a2[ks], bb, acc2, 0, 0, 0);
        }

        // ---- epilogue: sigmoid(logit + diffuse) ----
        if (row < 3) {
            #pragma unroll
            for (int r = 0; r < 4; ++r) {
                int pidx = t*16 + seg*4 + r;
                int pl   = wv*64 + pidx;
                float x  = acc2[r] + diff[pl*3 + row];
                float sg = 1.0f / (1.0f + __expf(-x));
                out[(blockIdx.x*256 + pl)*4 + row] = sg;
            }
        }
    }
}

extern "C" void kernel_launch(void* const* d_in, const int* in_sizes, int n_in,
                              void* d_out, int out_size, void* d_ws, size_t ws_size,
                              hipStream_t stream) {
    const float* pts = (const float*)d_in[0];
    const float* vd  = (const float*)d_in[1];
    const float* dg  = (const float*)d_in[2];
    const float* cg  = (const float*)d_in[3];
    const float* w0  = (const float*)d_in[4];
    const float* b0  = (const float*)d_in[5];
    const float* w1  = (const float*)d_in[6];
    const float* b1  = (const float*)d_in[7];
    const float* w2  = (const float*)d_in[8];
    const float* b2  = (const float*)d_in[9];
    float* out = (float*)d_out;

    const int n = in_sizes[0] / 3;        // 2097152 points
    const int blocks = n / 256;           // 8192, exact

    if (ws_size >= TG_BYTES) {
        short* tg = (short*)d_ws;
        make_tg<<<RES3/256, 256, 0, stream>>>(dg, cg, tg);   // 16000 blocks exact
        dvgo_fused<true><<<blocks, 256, 0, stream>>>(pts, vd, dg, cg, tg,
                                                     w0, b0, w1, b1, w2, b2, out);
    } else {
        dvgo_fused<false><<<blocks, 256, 0, stream>>>(pts, vd, dg, cg, nullptr,
                                                      w0, b0, w1, b1, w2, b2, out);
    }
}

// Round 3
// 287.772 us; speedup vs baseline: 7.5573x; 2.4541x over previous
//
#include <hip/hip_runtime.h>
#include <hip/hip_bf16.h>
#include <math.h>

#define RES   160
#define RES2  (160*160)
#define RES3  (160*160*160)
#define TG_ELEMS ((size_t)RES3 * 16)           // shorts
#define TG_BYTES (TG_ELEMS * 2)                // 131,072,000 B

// weight blob: A0 (12288 B) | A1 (32768 B) | b1p (512 B) | w2p (2048 B)
#define BLOB_BYTES  47616
#define BLOB_SHORTS 22528                      // A0 + A1 region in shorts
#define BLOB_FLOATS 640                        // b1p (128) + w2p (512)
#define A1_OFF      12288                      // bytes
#define B1P_OFF     45056                      // bytes
#define W2P_OFF     45568                      // bytes

typedef __attribute__((ext_vector_type(8)))  short s16x8;
typedef __attribute__((ext_vector_type(4)))  float f32x4;
typedef __attribute__((ext_vector_type(16))) float f32x16;
typedef __attribute__((ext_vector_type(4)))  int   i32x4;

__device__ __forceinline__ unsigned short f2bf(float x) {
    union { float f; unsigned u; } v; v.f = x;
    unsigned r = v.u + 0x7FFFu + ((v.u >> 16) & 1u);
    return (unsigned short)(r >> 16);
}
__device__ __forceinline__ unsigned pack2(float lo, float hi) {
    return (unsigned)f2bf(lo) | ((unsigned)f2bf(hi) << 16);
}
__device__ __forceinline__ float bf_lo(unsigned u) {
    union { unsigned u; float f; } v; v.u = u << 16; return v.f;
}
__device__ __forceinline__ float bf_hi(unsigned u) {
    union { unsigned u; float f; } v; v.u = u & 0xFFFF0000u; return v.f;
}
__device__ __forceinline__ unsigned cvtpk_relu(float a, float b) {
    float x = fmaxf(a, 0.0f), y = fmaxf(b, 0.0f);
    unsigned r;
    asm("v_cvt_pk_bf16_f32 %0, %1, %2" : "=v"(r) : "v"(x), "v"(y));
    return r;
}

// ---------- weight blob value functions (shared by prepack + fallback) ----------
// A0: slot ((wm*3+ks)*2+hi)*32+lo, elem e: A[n=wm*32+lo][k=ks*16+hi*8+e]
//     value = k<36 ? w0[k][n] : (k==36 ? b0[n] : 0)   (bias folded at k=36)
// A1: slot ((wm*8+ks)*2+hi)*32+lo: value = w1[k][n], k=ks*16+hi*8+e, n=wm*32+lo
__device__ __forceinline__ float blob_short_val(int i, const float* __restrict__ w0,
                                                const float* __restrict__ b0,
                                                const float* __restrict__ w1) {
    if (i < 6144) {
        int e = i & 7, s = i >> 3;
        int lo = s & 31, r = s >> 5;
        int hi = r & 1, t = r >> 1;            // t = wm*3 + ks
        int wm = t / 3, ks = t - wm * 3;
        int k = ks * 16 + hi * 8 + e, n = wm * 32 + lo;
        return k < 36 ? w0[k * 128 + n] : (k == 36 ? b0[n] : 0.0f);
    } else {
        int i2 = i - 6144;
        int e = i2 & 7, s = i2 >> 3;
        int lo = s & 31, r = s >> 5;
        int hi = r & 1, t = r >> 1;            // t = wm*8 + ks
        int wm = t >> 3, ks = t & 7;
        int k = ks * 16 + hi * 8 + e, n = wm * 32 + lo;
        return w1[k * 128 + n];
    }
}
// b1p[(wm*4+g)*8 + hi*4 + c] = b1[wm*32+8g+4hi+c]
// w2p[(wm*4+g)*32 + hi*16 + c*4 + cc] = w2[(wm*32+8g+4hi+c)*3+cc] (cc<3)
__device__ __forceinline__ float blob_float_val(int j, const float* __restrict__ b1,
                                                const float* __restrict__ w2) {
    if (j < 128) {
        int c = j & 3, r = j >> 2, hi = r & 1, t = r >> 1;
        int g = t & 3, wm = t >> 2;
        return b1[wm * 32 + 8 * g + 4 * hi + c];
    } else {
        int j2 = j - 128;
        int cc = j2 & 3, m = j2 >> 2;
        int c = m & 3, r = m >> 2, hi = r & 1, t = r >> 1;
        int g = t & 3, wm = t >> 2;
        return cc < 3 ? w2[(wm * 32 + 8 * g + 4 * hi + c) * 3 + cc] : 0.0f;
    }
}

// ---------------- transpose: [C,X,Y,Z] f32 -> [X,Y,Z,16] bf16 ----------------
__global__ __launch_bounds__(256) void make_tg(
    const float* __restrict__ dgrid, const float* __restrict__ cgrid,
    short* __restrict__ tg)
{
    const int v = blockIdx.x * 256 + threadIdx.x;
    float vals[13];
    #pragma unroll
    for (int c = 0; c < 12; ++c) vals[c] = cgrid[(size_t)c * RES3 + v];
    vals[12] = dgrid[v];

    i32x4 r0 = { (int)pack2(vals[0], vals[1]),  (int)pack2(vals[2],  vals[3]),
                 (int)pack2(vals[4], vals[5]),  (int)pack2(vals[6],  vals[7]) };
    i32x4 r1 = { (int)pack2(vals[8], vals[9]),  (int)pack2(vals[10], vals[11]),
                 (int)pack2(vals[12], 0.0f),    0 };
    *(i32x4*)&tg[(size_t)v * 16 + 0] = r0;
    *(i32x4*)&tg[(size_t)v * 16 + 8] = r1;
}

// ---------------- weight prepack ----------------
__global__ __launch_bounds__(256) void prepack(
    const float* __restrict__ w0, const float* __restrict__ b0,
    const float* __restrict__ w1, const float* __restrict__ b1,
    const float* __restrict__ w2, char* __restrict__ blob)
{
    int t = blockIdx.x * 256 + threadIdx.x;
    if (t < BLOB_SHORTS) {
        ((short*)blob)[t] = (short)f2bf(blob_short_val(t, w0, b0, w1));
    } else if (t < BLOB_SHORTS + BLOB_FLOATS) {
        int j = t - BLOB_SHORTS;
        ((float*)(blob + B1P_OFF))[j] = blob_float_val(j, b1, w2);
    }
}

// ---------------- fused gather + transposed-chain MLP ----------------
template<bool TG, bool PRE>
__global__ __launch_bounds__(256, 3) void dvgo_fused(
    const float* __restrict__ pts, const float* __restrict__ vdirs,
    const float* __restrict__ dgrid, const float* __restrict__ cgrid,
    const short* __restrict__ tg, const char* __restrict__ blob,
    const float* __restrict__ w0, const float* __restrict__ b0,
    const float* __restrict__ w1, const float* __restrict__ b1,
    const float* __restrict__ w2, const float* __restrict__ b2,
    float* __restrict__ out)
{
    __shared__ __align__(16) char smem[BLOB_BYTES];
    const int tid  = threadIdx.x;
    const int lane = tid & 63;
    const int wv   = tid >> 6;
    const int lo   = lane & 31;
    const int hi   = lane >> 5;

    // ---------- stage weights ----------
    if (PRE) {
        const i32x4* src = (const i32x4*)blob;
        i32x4* dst = (i32x4*)smem;
        for (int i = tid; i < BLOB_BYTES / 16; i += 256) dst[i] = src[i];
    } else {
        for (int i = tid; i < BLOB_SHORTS; i += 256)
            ((short*)smem)[i] = (short)f2bf(blob_short_val(i, w0, b0, w1));
        for (int i = tid; i < BLOB_FLOATS; i += 256)
            ((float*)(smem + B1P_OFF))[i] = blob_float_val(i, b1, w2);
    }

    // ---------- per-thread gather + feature build (own point) ----------
    const int p = blockIdx.x * 256 + tid;
    float P0 = pts[p*3+0], P1 = pts[p*3+1], P2 = pts[p*3+2];
    float V0 = vdirs[p*3+0], V1 = vdirs[p*3+1], V2 = vdirs[p*3+2];

    int   ii[3];
    float ff[3];
    float Pv[3] = {P0, P1, P2};
    #pragma unroll
    for (int d = 0; d < 3; ++d) {
        float u = (Pv[d] + 1.0f) * 79.5f;
        u = fminf(fmaxf(u, 0.0f), 159.0f);
        int i0 = (int)u;
        if (i0 > 158) i0 = 158;
        ii[d] = i0;
        ff[d] = u - (float)i0;
    }
    const float fx = ff[0], fy = ff[1], fz = ff[2];
    const float wxy0 = (1.0f-fx)*(1.0f-fy);
    const float wxy1 = (1.0f-fx)*fy;
    const float wxy2 = fx*(1.0f-fy);
    const float wxy3 = fx*fy;

    float dens;
    float col[12];

    if (TG) {
        const int base16 = ((ii[0]*RES + ii[1])*RES + ii[2]) * 16;
        const short* q00 = tg + base16;
        const short* q01 = q00 + RES*16;
        const short* q10 = q00 + RES2*16;
        const short* q11 = q10 + RES*16;

        float cv[13];
        #pragma unroll
        for (int c = 0; c < 13; ++c) cv[c] = 0.0f;

        const short* qs[4] = { q00, q01, q10, q11 };
        const float  ws[4] = { wxy0, wxy1, wxy2, wxy3 };
        #pragma unroll
        for (int cn = 0; cn < 4; ++cn) {
            const short* q = qs[cn];
            const float  w = ws[cn];
            i32x4 u0 = *(const i32x4*)(q);
            i32x4 u1 = *(const i32x4*)(q + 8);
            i32x4 u2 = *(const i32x4*)(q + 16);
            i32x4 u3 = *(const i32x4*)(q + 24);
            unsigned a[8] = { (unsigned)u0[0], (unsigned)u0[1], (unsigned)u0[2], (unsigned)u0[3],
                              (unsigned)u1[0], (unsigned)u1[1], (unsigned)u1[2], (unsigned)u1[3] };
            unsigned b[8] = { (unsigned)u2[0], (unsigned)u2[1], (unsigned)u2[2], (unsigned)u2[3],
                              (unsigned)u3[0], (unsigned)u3[1], (unsigned)u3[2], (unsigned)u3[3] };
            #pragma unroll
            for (int c = 0; c < 13; ++c) {
                float va = (c & 1) ? bf_hi(a[c >> 1]) : bf_lo(a[c >> 1]);
                float vb = (c & 1) ? bf_hi(b[c >> 1]) : bf_lo(b[c >> 1]);
                cv[c] += w * (va + fz * (vb - va));
            }
        }
        #pragma unroll
        for (int c = 0; c < 12; ++c) col[c] = cv[c];
        dens = cv[12];
    } else {
        const int base = (ii[0]*RES + ii[1])*RES + ii[2];
        const int o0 = base, o1 = base + RES, o2 = base + RES2, o3 = base + RES2 + RES;
        auto tl = [&](const float* __restrict__ g) -> float {
            float a0 = g[o0], a1 = g[o0+1];
            float c0 = g[o1], c1 = g[o1+1];
            float d0 = g[o2], d1 = g[o2+1];
            float e0 = g[o3], e1 = g[o3+1];
            float v0 = a0 + fz*(a1-a0);
            float v1 = c0 + fz*(c1-c0);
            float v2 = d0 + fz*(d1-d0);
            float v3 = e0 + fz*(e1-e0);
            return wxy0*v0 + wxy1*v1 + wxy2*v2 + wxy3*v3;
        };
        dens = tl(dgrid);
        #pragma unroll
        for (int c = 0; c < 12; ++c) col[c] = tl(cgrid + (size_t)c * RES3);
    }

    // feature: [k0_view(9), v(3), sin(12), cos(12), 1(bias), 0-pad] -> K=48
    float ft[36];
    #pragma unroll
    for (int j = 0; j < 9; ++j) ft[j] = col[3+j];
    ft[9] = V0; ft[10] = V1; ft[11] = V2;
    float Vv[3] = {V0, V1, V2};
    #pragma unroll
    for (int k = 0; k < 4; ++k) {
        float s = (float)(1 << k);
        #pragma unroll
        for (int d = 0; d < 3; ++d) {
            float a = Vv[d] * s;
            ft[12 + 3*k + d] = __sinf(a);
            ft[24 + 3*k + d] = __cosf(a);
        }
    }
    unsigned fpk[24];
    #pragma unroll
    for (int j = 0; j < 18; ++j) fpk[j] = pack2(ft[2*j], ft[2*j+1]);
    fpk[18] = pack2(1.0f, 0.0f);               // bias channel k=36
    #pragma unroll
    for (int j = 19; j < 24; ++j) fpk[j] = 0u;

    const float col0v = col[0], col1v = col[1], col2v = col[2];
    // partner's diffuse/density (for pt-tile 1 epilogue)
    const float scol0 = __shfl_xor(col0v, 32, 64);
    const float scol1 = __shfl_xor(col1v, 32, 64);
    const float scol2 = __shfl_xor(col2v, 32, 64);
    const float sdens = __shfl_xor(dens,  32, 64);
    const float b2v0 = b2[0], b2v1 = b2[1], b2v2 = b2[2];

    __syncthreads();   // weights staged; no further barriers

    const char*  a0p  = smem + lane * 16;              // + (wm*3+ks)*1024
    const char*  a1p  = smem + A1_OFF + lane * 16;     // + (wm*8+ks)*1024
    const float* b1ph = (const float*)(smem + B1P_OFF) + hi * 4;   // + (wm*4+g)*8
    const float* w2ph = (const float*)(smem + W2P_OFF) + hi * 16;  // + (wm*4+g)*32 + c*4

    // ---------- per-wave MFMA: 2 point-tiles of 32 (transposed chain) ----------
    #pragma unroll
    for (int pt = 0; pt < 2; ++pt) {
        // ===== layer 0: H1[128 x 32] = W0a[128 x 48] @ F[48 x 32] =====
        f32x16 acc0[4];
        #pragma unroll
        for (int w = 0; w < 4; ++w)
            #pragma unroll
            for (int r = 0; r < 16; ++r) acc0[w][r] = 0.0f;

        #pragma unroll
        for (int ks = 0; ks < 3; ++ks) {
            unsigned bfr[4];
            #pragma unroll
            for (int d = 0; d < 4; ++d) {
                unsigned own_hi = fpk[ks*8 + 4 + d];
                unsigned own_lo = fpk[ks*8 + d];
                unsigned sw = (unsigned)__shfl_xor((int)(pt == 0 ? own_hi : own_lo), 32, 64);
                bfr[d] = (pt == 0) ? (hi ? sw : own_lo) : (hi ? own_hi : sw);
            }
            i32x4 bi = { (int)bfr[0], (int)bfr[1], (int)bfr[2], (int)bfr[3] };
            s16x8 B = __builtin_bit_cast(s16x8, bi);
            #pragma unroll
            for (int w = 0; w < 4; ++w) {
                s16x8 A = *(const s16x8*)(a0p + (w*3 + ks) * 1024);
                acc0[w] = __builtin_amdgcn_mfma_f32_32x32x16_bf16(A, B, acc0[w], 0, 0, 0);
            }
        }

        // relu + pack to bf16 pairs: u1[wm][2g+b] = pair j = wm*16+4g+2hi+b
        unsigned u1[4][8];
        #pragma unroll
        for (int w = 0; w < 4; ++w)
            #pragma unroll
            for (int g = 0; g < 4; ++g) {
                u1[w][2*g+0] = cvtpk_relu(acc0[w][4*g+0], acc0[w][4*g+1]);
                u1[w][2*g+1] = cvtpk_relu(acc0[w][4*g+2], acc0[w][4*g+3]);
            }

        // ===== layer 1: H2[128 x 32] = W1a[128 x 128] @ H1 + b1 =====
        f32x16 acc1[4];
        #pragma unroll
        for (int w = 0; w < 4; ++w)
            #pragma unroll
            for (int g = 0; g < 4; ++g) {
                f32x4 bv = *(const f32x4*)(b1ph + (w*4 + g) * 8);
                acc1[w][4*g+0] = bv[0]; acc1[w][4*g+1] = bv[1];
                acc1[w][4*g+2] = bv[2]; acc1[w][4*g+3] = bv[3];
            }
        #pragma unroll
        for (int ks = 0; ks < 8; ++ks) {
            const int wsrc = ks >> 1, q = 4 * (ks & 1);
            unsigned su[4];
            #pragma unroll
            for (int i = 0; i < 4; ++i)
                su[i] = (unsigned)__shfl_xor((int)u1[wsrc][q + i], 32, 64);
            unsigned bfr[4];
            bfr[0] = hi ? su[2]            : u1[wsrc][q+0];
            bfr[1] = hi ? su[3]            : u1[wsrc][q+1];
            bfr[2] = hi ? u1[wsrc][q+2]    : su[0];
            bfr[3] = hi ? u1[wsrc][q+3]    : su[1];
            i32x4 bi = { (int)bfr[0], (int)bfr[1], (int)bfr[2], (int)bfr[3] };
            s16x8 B = __builtin_bit_cast(s16x8, bi);
            #pragma unroll
            for (int w = 0; w < 4; ++w) {
                s16x8 A = *(const s16x8*)(a1p + (w*8 + ks) * 1024);
                acc1[w] = __builtin_amdgcn_mfma_f32_32x32x16_bf16(A, B, acc1[w], 0, 0, 0);
            }
        }

        // ===== layer 2 (128 -> 3) via VALU dot on acc registers =====
        float p0 = 0.0f, p1 = 0.0f, p2 = 0.0f;
        #pragma unroll
        for (int w = 0; w < 4; ++w)
            #pragma unroll
            for (int g = 0; g < 4; ++g) {
                const float* wrow = w2ph + (w*4 + g) * 32;
                #pragma unroll
                for (int c = 0; c < 4; ++c) {
                    float v = fmaxf(acc1[w][4*g+c], 0.0f);
                    f32x4 wvv = *(const f32x4*)(wrow + c * 4);
                    p0 += v * wvv[0]; p1 += v * wvv[1]; p2 += v * wvv[2];
                }
            }
        p0 += __shfl_xor(p0, 32, 64);
        p1 += __shfl_xor(p1, 32, 64);
        p2 += __shfl_xor(p2, 32, 64);

        const float d0 = pt ? scol0 : col0v;
        const float d1 = pt ? scol1 : col1v;
        const float d2 = pt ? scol2 : col2v;
        const float dn = pt ? sdens : dens;
        if (hi == 0) {
            float x0 = p0 + b2v0 + d0;
            float x1 = p1 + b2v1 + d1;
            float x2 = p2 + b2v2 + d2;
            f32x4 o = { 1.0f / (1.0f + __expf(-x0)),
                        1.0f / (1.0f + __expf(-x1)),
                        1.0f / (1.0f + __expf(-x2)),
                        dn };
            const int gp = blockIdx.x * 256 + wv * 64 + pt * 32 + lo;
            *(f32x4*)(out + (size_t)gp * 4) = o;
        }
    }
}

extern "C" void kernel_launch(void* const* d_in, const int* in_sizes, int n_in,
                              void* d_out, int out_size, void* d_ws, size_t ws_size,
                              hipStream_t stream) {
    const float* pts = (const float*)d_in[0];
    const float* vd  = (const float*)d_in[1];
    const float* dg  = (const float*)d_in[2];
    const float* cg  = (const float*)d_in[3];
    const float* w0  = (const float*)d_in[4];
    const float* b0  = (const float*)d_in[5];
    const float* w1  = (const float*)d_in[6];
    const float* b1  = (const float*)d_in[7];
    const float* w2  = (const float*)d_in[8];
    const float* b2  = (const float*)d_in[9];
    float* out = (float*)d_out;

    const int n = in_sizes[0] / 3;        // 2097152 points
    const int blocks = n / 256;           // 8192

    if (ws_size >= TG_BYTES + BLOB_BYTES) {
        short* tg = (short*)d_ws;
        char* blob = (char*)d_ws + TG_BYTES;
        make_tg<<<RES3/256, 256, 0, stream>>>(dg, cg, tg);
        prepack<<<(BLOB_SHORTS + BLOB_FLOATS + 255)/256, 256, 0, stream>>>(w0, b0, w1, b1, w2, blob);
        dvgo_fused<true, true><<<blocks, 256, 0, stream>>>(
            pts, vd, dg, cg, tg, blob, w0, b0, w1, b1, w2, b2, out);
    } else if (ws_size >= TG_BYTES) {
        short* tg = (short*)d_ws;
        make_tg<<<RES3/256, 256, 0, stream>>>(dg, cg, tg);
        dvgo_fused<true, false><<<blocks, 256, 0, stream>>>(
            pts, vd, dg, cg, tg, nullptr, w0, b0, w1, b1, w2, b2, out);
    } else {
        dvgo_fused<false, false><<<blocks, 256, 0, stream>>>(
            pts, vd, dg, cg, nullptr, nullptr, w0, b0, w1, b1, w2, b2, out);
    }
}

// Round 4
// 271.652 us; speedup vs baseline: 8.0058x; 1.0593x over previous
//
#include <hip/hip_runtime.h>
#include <hip/hip_bf16.h>
#include <math.h>

#define RES   160
#define RES2  (160*160)
#define RES3  (160*160*160)
#define TG_ELEMS ((size_t)RES3 * 16)           // shorts
#define TG_BYTES (TG_ELEMS * 2)                // 131,072,000 B

// weight blob: A0 (12288 B) | A1 (32768 B) | b1p (512 B) | w2p (1536 B)
#define BLOB_BYTES  47104
#define BLOB_SHORTS 22528                      // A0 + A1 region in shorts
#define BLOB_FLOATS 512                        // b1p (128) + w2p (384)
#define A1_OFF      12288                      // bytes
#define B1P_OFF     45056                      // bytes
#define W2P_OFF     45568                      // bytes

typedef __attribute__((ext_vector_type(8)))  short s16x8;
typedef __attribute__((ext_vector_type(2)))  float f32x2;
typedef __attribute__((ext_vector_type(4)))  float f32x4;
typedef __attribute__((ext_vector_type(16))) float f32x16;
typedef __attribute__((ext_vector_type(4)))  int   i32x4;

__device__ __forceinline__ unsigned short f2bf(float x) {
    union { float f; unsigned u; } v; v.f = x;
    unsigned r = v.u + 0x7FFFu + ((v.u >> 16) & 1u);
    return (unsigned short)(r >> 16);
}
__device__ __forceinline__ unsigned cvtpk(float lo, float hi) {
    unsigned r;
    asm("v_cvt_pk_bf16_f32 %0, %1, %2" : "=v"(r) : "v"(lo), "v"(hi));
    return r;
}
__device__ __forceinline__ float bf_lo(unsigned u) {
    union { unsigned u; float f; } v; v.u = u << 16; return v.f;
}
__device__ __forceinline__ float bf_hi(unsigned u) {
    union { unsigned u; float f; } v; v.u = u & 0xFFFF0000u; return v.f;
}
__device__ __forceinline__ unsigned cvtpk_relu(float a, float b) {
    return cvtpk(fmaxf(a, 0.0f), fmaxf(b, 0.0f));
}
// a' = [a.lo, b.lo], b' = [a.hi, b.hi]  (swap a's hi half with b's lo half)
__device__ __forceinline__ void plswap(unsigned &a, unsigned &b) {
    asm("v_permlane32_swap_b32 %0, %1" : "+v"(a), "+v"(b));
}
__device__ __forceinline__ float sum_halves(float x) {
    unsigned a = __float_as_uint(x), b = a;
    plswap(a, b);                    // a=[lo,lo], b=[hi,hi]
    return __uint_as_float(a) + __uint_as_float(b);
}
__device__ __forceinline__ f32x2 pkfma(f32x2 a, f32x2 b, f32x2 c) {
    f32x2 r;
    asm("v_pk_fma_f32 %0, %1, %2, %3" : "=v"(r) : "v"(a), "v"(b), "v"(c));
    return r;
}
__device__ __forceinline__ f32x2 pkmul(f32x2 a, f32x2 b) {
    f32x2 r;
    asm("v_pk_mul_f32 %0, %1, %2" : "=v"(r) : "v"(a), "v"(b));
    return r;
}

// ---------- weight blob value functions (shared by prepack + fallback) ----------
// A0: slot ((wm*3+ks)*2+hi)*32+lo, elem e: value = A[n=wm*32+lo][k=ks*16+hi*8+e]
//     = k<36 ? w0[k][n] : (k==36 ? b0[n] : 0)   (bias folded at k=36)
// A1: slot ((wm*8+ks)*2+hi)*32+lo: value = w1[k][n]
__device__ __forceinline__ float blob_short_val(int i, const float* __restrict__ w0,
                                                const float* __restrict__ b0,
                                                const float* __restrict__ w1) {
    if (i < 6144) {
        int e = i & 7, s = i >> 3;
        int lo = s & 31, r = s >> 5;
        int hi = r & 1, t = r >> 1;            // t = wm*3 + ks
        int wm = t / 3, ks = t - wm * 3;
        int k = ks * 16 + hi * 8 + e, n = wm * 32 + lo;
        return k < 36 ? w0[k * 128 + n] : (k == 36 ? b0[n] : 0.0f);
    } else {
        int i2 = i - 6144;
        int e = i2 & 7, s = i2 >> 3;
        int lo = s & 31, r = s >> 5;
        int hi = r & 1, t = r >> 1;            // t = wm*8 + ks
        int wm = t >> 3, ks = t & 7;
        int k = ks * 16 + hi * 8 + e, n = wm * 32 + lo;
        return w1[k * 128 + n];
    }
}
// b1p[(wm*4+g)*8 + hi*4 + c] = b1[wm*32+8g+4hi+c]
// w2p[(((wm*4+g)*2+hi)*3 + cc)*4 + c] = w2[(wm*32+8g+4hi+c)*3 + cc]
__device__ __forceinline__ float blob_float_val(int j, const float* __restrict__ b1,
                                                const float* __restrict__ w2) {
    if (j < 128) {
        int c = j & 3, r = j >> 2, hi = r & 1, t = r >> 1;
        int g = t & 3, wm = t >> 2;
        return b1[wm * 32 + 8 * g + 4 * hi + c];
    } else {
        int j2 = j - 128;                      // 0..383
        int c  = j2 & 3;
        int t  = j2 >> 2;                      // ((wm*4+g)*2+hi)*3 + cc
        int cc = t % 3;
        int u  = t / 3;
        int hi = u & 1, v = u >> 1;
        int g  = v & 3, wm = v >> 2;
        return w2[(wm * 32 + 8 * g + 4 * hi + c) * 3 + cc];
    }
}

// ---------------- transpose: [C,X,Y,Z] f32 -> [X,Y,Z,16] bf16 ----------------
__global__ __launch_bounds__(256) void make_tg(
    const float* __restrict__ dgrid, const float* __restrict__ cgrid,
    short* __restrict__ tg)
{
    const int v = blockIdx.x * 256 + threadIdx.x;
    float vals[13];
    #pragma unroll
    for (int c = 0; c < 12; ++c) vals[c] = cgrid[(size_t)c * RES3 + v];
    vals[12] = dgrid[v];

    i32x4 r0 = { (int)cvtpk(vals[0], vals[1]),  (int)cvtpk(vals[2],  vals[3]),
                 (int)cvtpk(vals[4], vals[5]),  (int)cvtpk(vals[6],  vals[7]) };
    i32x4 r1 = { (int)cvtpk(vals[8], vals[9]),  (int)cvtpk(vals[10], vals[11]),
                 (int)cvtpk(vals[12], 0.0f),    0 };
    *(i32x4*)&tg[(size_t)v * 16 + 0] = r0;
    *(i32x4*)&tg[(size_t)v * 16 + 8] = r1;
}

// ---------------- weight prepack ----------------
__global__ __launch_bounds__(256) void prepack(
    const float* __restrict__ w0, const float* __restrict__ b0,
    const float* __restrict__ w1, const float* __restrict__ b1,
    const float* __restrict__ w2, char* __restrict__ blob)
{
    int t = blockIdx.x * 256 + threadIdx.x;
    if (t < BLOB_SHORTS) {
        ((short*)blob)[t] = (short)f2bf(blob_short_val(t, w0, b0, w1));
    } else if (t < BLOB_SHORTS + BLOB_FLOATS) {
        int j = t - BLOB_SHORTS;
        ((float*)(blob + B1P_OFF))[j] = blob_float_val(j, b1, w2);
    }
}

// ---------------- fused gather + transposed-chain MLP ----------------
template<bool TG, bool PRE>
__global__ __launch_bounds__(256, 3) void dvgo_fused(
    const float* __restrict__ pts, const float* __restrict__ vdirs,
    const float* __restrict__ dgrid, const float* __restrict__ cgrid,
    const short* __restrict__ tg, const char* __restrict__ blob,
    const float* __restrict__ w0, const float* __restrict__ b0,
    const float* __restrict__ w1, const float* __restrict__ b1,
    const float* __restrict__ w2, const float* __restrict__ b2,
    float* __restrict__ out)
{
    __shared__ __align__(16) char smem[BLOB_BYTES];
    const int tid  = threadIdx.x;
    const int lane = tid & 63;
    const int wv   = tid >> 6;
    const int lo   = lane & 31;
    const int hi   = lane >> 5;

    // ---------- stage weights ----------
    if (PRE) {
        const i32x4* src = (const i32x4*)blob;
        i32x4* dst = (i32x4*)smem;
        for (int i = tid; i < BLOB_BYTES / 16; i += 256) dst[i] = src[i];
    } else {
        for (int i = tid; i < BLOB_SHORTS; i += 256)
            ((short*)smem)[i] = (short)f2bf(blob_short_val(i, w0, b0, w1));
        for (int i = tid; i < BLOB_FLOATS; i += 256)
            ((float*)(smem + B1P_OFF))[i] = blob_float_val(i, b1, w2);
    }

    // ---------- per-thread gather + feature build (own point) ----------
    const int p = blockIdx.x * 256 + tid;
    float P0 = pts[p*3+0], P1 = pts[p*3+1], P2 = pts[p*3+2];
    float V0 = vdirs[p*3+0], V1 = vdirs[p*3+1], V2 = vdirs[p*3+2];

    int   ii[3];
    float ff[3];
    float Pv[3] = {P0, P1, P2};
    #pragma unroll
    for (int d = 0; d < 3; ++d) {
        float u = (Pv[d] + 1.0f) * 79.5f;
        u = fminf(fmaxf(u, 0.0f), 159.0f);
        int i0 = (int)u;
        if (i0 > 158) i0 = 158;
        ii[d] = i0;
        ff[d] = u - (float)i0;
    }
    const float fx = ff[0], fy = ff[1], fz = ff[2];
    const float wxy0 = (1.0f-fx)*(1.0f-fy);
    const float wxy1 = (1.0f-fx)*fy;
    const float wxy2 = fx*(1.0f-fy);
    const float wxy3 = fx*fy;

    float dens;
    float col[12];

    if (TG) {
        const int base16 = ((ii[0]*RES + ii[1])*RES + ii[2]) * 16;
        const short* q00 = tg + base16;
        const short* q01 = q00 + RES*16;
        const short* q10 = q00 + RES2*16;
        const short* q11 = q10 + RES*16;

        f32x2 cv[7];
        #pragma unroll
        for (int pr = 0; pr < 7; ++pr) cv[pr] = f32x2{0.0f, 0.0f};

        const f32x2 fzv   = { fz, fz };
        const f32x2 omfzv = { 1.0f - fz, 1.0f - fz };

        const short* qs[4] = { q00, q01, q10, q11 };
        const float  wsx[4] = { wxy0, wxy1, wxy2, wxy3 };
        #pragma unroll
        for (int cn = 0; cn < 4; ++cn) {
            const short* q = qs[cn];
            i32x4 u0 = *(const i32x4*)(q);       // z voxel, ch0..7
            i32x4 u1v = *(const i32x4*)(q + 8);  // z voxel, ch8..15
            i32x4 u2 = *(const i32x4*)(q + 16);  // z+1 voxel, ch0..7
            i32x4 u3 = *(const i32x4*)(q + 24);  // z+1 voxel, ch8..15
            unsigned av[8] = { (unsigned)u0[0], (unsigned)u0[1], (unsigned)u0[2], (unsigned)u0[3],
                               (unsigned)u1v[0], (unsigned)u1v[1], (unsigned)u1v[2], (unsigned)u1v[3] };
            unsigned bv[8] = { (unsigned)u2[0], (unsigned)u2[1], (unsigned)u2[2], (unsigned)u2[3],
                               (unsigned)u3[0], (unsigned)u3[1], (unsigned)u3[2], (unsigned)u3[3] };
            const f32x2 wv2 = { wsx[cn], wsx[cn] };
            #pragma unroll
            for (int pr = 0; pr < 7; ++pr) {
                f32x2 va = { bf_lo(av[pr]), bf_hi(av[pr]) };
                f32x2 vb = { bf_lo(bv[pr]), bf_hi(bv[pr]) };
                f32x2 lz = pkfma(fzv, vb, pkmul(omfzv, va));   // va + fz*(vb-va)
                cv[pr] = pkfma(wv2, lz, cv[pr]);
            }
        }
        #pragma unroll
        for (int c = 0; c < 12; ++c) col[c] = (c & 1) ? cv[c >> 1].y : cv[c >> 1].x;
        dens = cv[6].x;
    } else {
        const int base = (ii[0]*RES + ii[1])*RES + ii[2];
        const int o0 = base, o1 = base + RES, o2 = base + RES2, o3 = base + RES2 + RES;
        auto tl = [&](const float* __restrict__ g) -> float {
            float a0 = g[o0], a1 = g[o0+1];
            float c0 = g[o1], c1 = g[o1+1];
            float d0 = g[o2], d1 = g[o2+1];
            float e0 = g[o3], e1 = g[o3+1];
            float v0 = a0 + fz*(a1-a0);
            float v1 = c0 + fz*(c1-c0);
            float v2 = d0 + fz*(d1-d0);
            float v3 = e0 + fz*(e1-e0);
            return wxy0*v0 + wxy1*v1 + wxy2*v2 + wxy3*v3;
        };
        dens = tl(dgrid);
        #pragma unroll
        for (int c = 0; c < 12; ++c) col[c] = tl(cgrid + (size_t)c * RES3);
    }

    // feature: [k0_view(9), v(3), sin(12), cos(12), 1(bias), 0-pad] -> K=48
    float ft[36];
    #pragma unroll
    for (int j = 0; j < 9; ++j) ft[j] = col[3+j];
    ft[9] = V0; ft[10] = V1; ft[11] = V2;
    float Vv[3] = {V0, V1, V2};
    #pragma unroll
    for (int d = 0; d < 3; ++d) {
        float s1, c1;
        __sincosf(Vv[d], &s1, &c1);
        float s2 = 2.0f*s1*c1,  c2 = __builtin_fmaf(-2.0f*s1, s1, 1.0f);
        float s4 = 2.0f*s2*c2,  c4 = __builtin_fmaf(-2.0f*s2, s2, 1.0f);
        float s8 = 2.0f*s4*c4,  c8 = __builtin_fmaf(-2.0f*s4, s4, 1.0f);
        ft[12 + d] = s1; ft[15 + d] = s2; ft[18 + d] = s4; ft[21 + d] = s8;
        ft[24 + d] = c1; ft[27 + d] = c2; ft[30 + d] = c4; ft[33 + d] = c8;
    }
    unsigned fpk[24];
    #pragma unroll
    for (int j = 0; j < 18; ++j) fpk[j] = cvtpk(ft[2*j], ft[2*j+1]);
    fpk[18] = cvtpk(1.0f, 0.0f);               // bias channel k=36
    #pragma unroll
    for (int j = 19; j < 24; ++j) fpk[j] = 0u;

    // pre-swap L0 B-fragments: after swap, fpk[ks*8 + 4*pt + d] is reg d for tile pt
    #pragma unroll
    for (int ks = 0; ks < 3; ++ks)
        #pragma unroll
        for (int d = 0; d < 4; ++d)
            plswap(fpk[ks*8 + d], fpk[ks*8 + 4 + d]);

    const float col0v = col[0], col1v = col[1], col2v = col[2];
    const float scol0 = __shfl_xor(col0v, 32, 64);
    const float scol1 = __shfl_xor(col1v, 32, 64);
    const float scol2 = __shfl_xor(col2v, 32, 64);
    const float sdens = __shfl_xor(dens,  32, 64);
    const float b2v0 = b2[0], b2v1 = b2[1], b2v2 = b2[2];

    __syncthreads();   // weights staged; no further barriers

    const char*  a0p  = smem + lane * 16;              // + (wm*3+ks)*1024
    const char*  a1p  = smem + A1_OFF + lane * 16;     // + (wm*8+ks)*1024
    const float* b1ph = (const float*)(smem + B1P_OFF) + hi * 4;   // + (wm*4+g)*8
    const float* w2ph = (const float*)(smem + W2P_OFF) + hi * 12;  // + (wm*4+g)*24

    // ---------- per-wave MFMA: 2 point-tiles of 32 (transposed chain) ----------
    #pragma unroll
    for (int pt = 0; pt < 2; ++pt) {
        // ===== layer 0: H1[128 x 32] = W0a[128 x 48] @ F[48 x 32] =====
        f32x16 acc0[4];
        #pragma unroll
        for (int w = 0; w < 4; ++w)
            #pragma unroll
            for (int r = 0; r < 16; ++r) acc0[w][r] = 0.0f;

        #pragma unroll
        for (int ks = 0; ks < 3; ++ks) {
            i32x4 bi = { (int)fpk[ks*8 + 4*pt + 0], (int)fpk[ks*8 + 4*pt + 1],
                         (int)fpk[ks*8 + 4*pt + 2], (int)fpk[ks*8 + 4*pt + 3] };
            s16x8 B = __builtin_bit_cast(s16x8, bi);
            #pragma unroll
            for (int w = 0; w < 4; ++w) {
                s16x8 A = *(const s16x8*)(a0p + (w*3 + ks) * 1024);
                acc0[w] = __builtin_amdgcn_mfma_f32_32x32x16_bf16(A, B, acc0[w], 0, 0, 0);
            }
        }

        // relu + pack to bf16 pairs
        unsigned u1[4][8];
        #pragma unroll
        for (int w = 0; w < 4; ++w)
            #pragma unroll
            for (int g = 0; g < 4; ++g) {
                u1[w][2*g+0] = cvtpk_relu(acc0[w][4*g+0], acc0[w][4*g+1]);
                u1[w][2*g+1] = cvtpk_relu(acc0[w][4*g+2], acc0[w][4*g+3]);
            }

        // ===== layer 1: H2[128 x 32] = W1a[128 x 128] @ H1 + b1 =====
        f32x16 acc1[4];
        #pragma unroll
        for (int w = 0; w < 4; ++w)
            #pragma unroll
            for (int g = 0; g < 4; ++g) {
                f32x4 bv = *(const f32x4*)(b1ph + (w*4 + g) * 8);
                acc1[w][4*g+0] = bv[0]; acc1[w][4*g+1] = bv[1];
                acc1[w][4*g+2] = bv[2]; acc1[w][4*g+3] = bv[3];
            }
        #pragma unroll
        for (int ks = 0; ks < 8; ++ks) {
            const int w = ks >> 1, q = 4 * (ks & 1);
            plswap(u1[w][q+0], u1[w][q+2]);    // in-place -> B fragment regs
            plswap(u1[w][q+1], u1[w][q+3]);
            i32x4 bi = { (int)u1[w][q+0], (int)u1[w][q+1],
                         (int)u1[w][q+2], (int)u1[w][q+3] };
            s16x8 B = __builtin_bit_cast(s16x8, bi);
            #pragma unroll
            for (int wm = 0; wm < 4; ++wm) {
                s16x8 A = *(const s16x8*)(a1p + (wm*8 + ks) * 1024);
                acc1[wm] = __builtin_amdgcn_mfma_f32_32x32x16_bf16(A, B, acc1[wm], 0, 0, 0);
            }
        }

        // ===== layer 2 (128 -> 3) via packed-f32 dot on acc registers =====
        f32x2 pa0 = {0.0f, 0.0f}, pa1 = {0.0f, 0.0f}, pa2 = {0.0f, 0.0f};
        #pragma unroll
        for (int w = 0; w < 4; ++w)
            #pragma unroll
            for (int g = 0; g < 4; ++g) {
                const float* wrow = w2ph + (w*4 + g) * 24;
                f32x4 q0 = *(const f32x4*)(wrow + 0);   // cc=0: c0,c1,c2,c3
                f32x4 q1 = *(const f32x4*)(wrow + 4);   // cc=1
                f32x4 q2 = *(const f32x4*)(wrow + 8);   // cc=2
                f32x2 v01 = { fmaxf(acc1[w][4*g+0], 0.0f), fmaxf(acc1[w][4*g+1], 0.0f) };
                f32x2 v23 = { fmaxf(acc1[w][4*g+2], 0.0f), fmaxf(acc1[w][4*g+3], 0.0f) };
                pa0 = pkfma(v01, f32x2{q0[0], q0[1]}, pa0);
                pa0 = pkfma(v23, f32x2{q0[2], q0[3]}, pa0);
                pa1 = pkfma(v01, f32x2{q1[0], q1[1]}, pa1);
                pa1 = pkfma(v23, f32x2{q1[2], q1[3]}, pa1);
                pa2 = pkfma(v01, f32x2{q2[0], q2[1]}, pa2);
                pa2 = pkfma(v23, f32x2{q2[2], q2[3]}, pa2);
            }
        float p0 = sum_halves(pa0.x + pa0.y);
        float p1 = sum_halves(pa1.x + pa1.y);
        float p2 = sum_halves(pa2.x + pa2.y);

        const float d0 = pt ? scol0 : col0v;
        const float d1 = pt ? scol1 : col1v;
        const float d2 = pt ? scol2 : col2v;
        const float dn = pt ? sdens : dens;
        if (hi == 0) {
            float x0 = p0 + b2v0 + d0;
            float x1 = p1 + b2v1 + d1;
            float x2 = p2 + b2v2 + d2;
            f32x4 o = { 1.0f / (1.0f + __expf(-x0)),
                        1.0f / (1.0f + __expf(-x1)),
                        1.0f / (1.0f + __expf(-x2)),
                        dn };
            const int gp = blockIdx.x * 256 + wv * 64 + pt * 32 + lo;
            *(f32x4*)(out + (size_t)gp * 4) = o;
        }
    }
}

extern "C" void kernel_launch(void* const* d_in, const int* in_sizes, int n_in,
                              void* d_out, int out_size, void* d_ws, size_t ws_size,
                              hipStream_t stream) {
    const float* pts = (const float*)d_in[0];
    const float* vd  = (const float*)d_in[1];
    const float* dg  = (const float*)d_in[2];
    const float* cg  = (const float*)d_in[3];
    const float* w0  = (const float*)d_in[4];
    const float* b0  = (const float*)d_in[5];
    const float* w1  = (const float*)d_in[6];
    const float* b1  = (const float*)d_in[7];
    const float* w2  = (const float*)d_in[8];
    const float* b2  = (const float*)d_in[9];
    float* out = (float*)d_out;

    const int n = in_sizes[0] / 3;        // 2097152 points
    const int blocks = n / 256;           // 8192

    if (ws_size >= TG_BYTES + BLOB_BYTES) {
        short* tg = (short*)d_ws;
        char* blob = (char*)d_ws + TG_BYTES;
        make_tg<<<RES3/256, 256, 0, stream>>>(dg, cg, tg);
        prepack<<<(BLOB_SHORTS + BLOB_FLOATS + 255)/256, 256, 0, stream>>>(w0, b0, w1, b1, w2, blob);
        dvgo_fused<true, true><<<blocks, 256, 0, stream>>>(
            pts, vd, dg, cg, tg, blob, w0, b0, w1, b1, w2, b2, out);
    } else if (ws_size >= TG_BYTES) {
        short* tg = (short*)d_ws;
        make_tg<<<RES3/256, 256, 0, stream>>>(dg, cg, tg);
        dvgo_fused<true, false><<<blocks, 256, 0, stream>>>(
            pts, vd, dg, cg, tg, nullptr, w0, b0, w1, b1, w2, b2, out);
    } else {
        dvgo_fused<false, false><<<blocks, 256, 0, stream>>>(
            pts, vd, dg, cg, nullptr, nullptr, w0, b0, w1, b1, w2, b2, out);
    }
}